// Round 3
// baseline (227.022 us; speedup 1.0000x reference)
//
#include <hip/hip_runtime.h>

// QuantizedSpectralConv on MI355X (gfx950).
// x [8,32,256,256] f32; Tucker: core[16,16,16,9] F0[32,16] F1[32,16] F2[32,16]
// F3[17,9] complex, deq = q*scale+min. Active window: kx in [112,144),
// ky in [56,73) of the (256,129) rfft2. norm="forward" (1/65536 on fwd).
//
// Workspace (float2):
//   A1 [17 ky][256 bi][256 h]; X [544 mode][256 bi]; W4 [544][32][32];
//   Mx [544 mode][256 bo];     CL [17 d][16 k][256 ij]  (F3-contracted core)
// LDS rule: addresses wave-uniform (broadcast) or lane-consecutive only.

__device__ __forceinline__ float2 cfma(float2 a, float2 b, float2 c) {
    c.x = fmaf(a.x, b.x, fmaf(-a.y, b.y, c.x));
    c.y = fmaf(a.x, b.y, fmaf(a.y, b.x, c.y));
    return c;
}
__device__ __forceinline__ float2 cmul(float2 a, float2 b) {
    return make_float2(a.x*b.x - a.y*b.y, a.x*b.y + a.y*b.x);
}

// ============ wprep: CL[d][k][ij] = sum_l core[ij,k,l] * F3[d,l] ============
__global__ __launch_bounds__(256) void wprep_kernel(
    const int* __restrict__ q_core, const int* __restrict__ q_f3,
    const float* __restrict__ core_scale, const float* __restrict__ core_min,
    const float* __restrict__ f_scales, const float* __restrict__ f_mins,
    float2* __restrict__ CL)
{
    int d = blockIdx.x >> 4, k = blockIdx.x & 15;   // grid 272
    int ij = threadIdx.x;
    float cs = *core_scale, cm = *core_min;
    float s3 = f_scales[3], m3 = f_mins[3];
    const int* qc = q_core + ((ij*16 + k)*9)*2;
    float2 acc = make_float2(0.f, 0.f);
#pragma unroll
    for (int l = 0; l < 9; ++l) {
        int2 q = *(const int2*)(qc + l*2);
        float2 ce = make_float2(q.x*cs + cm, q.y*cs + cm);
        float2 f3 = make_float2(q_f3[(d*9+l)*2]*s3 + m3, q_f3[(d*9+l)*2+1]*s3 + m3);
        acc = cfma(ce, f3, acc);
    }
    CL[(d*16 + k)*256 + ij] = acc;
}

// ============ weights: per-mode k/j/i contractions, CL coalesced ============
__global__ __launch_bounds__(256) void weights_kernel(
    const float2* __restrict__ CL, const int* __restrict__ q_f0,
    const int* __restrict__ q_f1, const int* __restrict__ q_f2,
    const float* __restrict__ f_scales, const float* __restrict__ f_mins,
    float2* __restrict__ W4)
{
    __shared__ float2 F0s[512], F1s[512];
    __shared__ float2 C2p[16*17];
    __shared__ float2 A2p[16*33];
    int t = threadIdx.x, m = blockIdx.x;
    int c = m / 17, d = m % 17;
    float s0 = f_scales[0], m0 = f_mins[0];
    float s1 = f_scales[1], m1 = f_mins[1];
    float s2 = f_scales[2], m2 = f_mins[2];

    for (int e = t; e < 512; e += 256) {
        F0s[e] = make_float2(q_f0[2*e]*s0 + m0, q_f0[2*e+1]*s0 + m0);
        F1s[e] = make_float2(q_f1[2*e]*s1 + m1, q_f1[2*e+1]*s1 + m1);
    }
    {   // phase 1: C2[i,j] = sum_k CL[d][k][ij] * F2[c,k]   (coalesced reads)
        float2 acc = make_float2(0.f, 0.f);
#pragma unroll
        for (int k = 0; k < 16; ++k) {
            float2 clv = CL[(d*16 + k)*256 + t];
            float2 f2 = make_float2(q_f2[(c*16+k)*2]*s2 + m2,
                                    q_f2[(c*16+k)*2+1]*s2 + m2);
            acc = cfma(clv, f2, acc);
        }
        __syncthreads();            // F0s/F1s ready; also before C2p write is fine
        C2p[(t >> 4)*17 + (t & 15)] = acc;
    }
    __syncthreads();
#pragma unroll
    for (int r = 0; r < 2; ++r) {   // phase 2: A2[i,b] = sum_j C2[i,j]*F1[b,j]
        int e = t + r*256; int i = e & 15, b = e >> 4;
        float2 acc = make_float2(0.f, 0.f);
#pragma unroll
        for (int j = 0; j < 16; ++j)
            acc = cfma(C2p[i*17 + j], F1s[b*16 + j], acc);
        A2p[i*33 + b] = acc;
    }
    __syncthreads();
    {   // phase 3: W4[m,a,b] = sum_i F0[a,i]*A2[i,b]
        int b = t & 31, a0 = t >> 5;
#pragma unroll
        for (int q = 0; q < 4; ++q) {
            int a = a0 + 8*q;
            float2 acc = make_float2(0.f, 0.f);
#pragma unroll
            for (int i = 0; i < 16; ++i)
                acc = cfma(F0s[a*16 + i], A2p[i*33 + b], acc);
            W4[m*1024 + a*32 + b] = acc;
        }
    }
}

// ================= forward partial DFT along w =================
// Register twiddle recurrence (no LDS table); quadrant signs wired.
template<int P>
__device__ __forceinline__ void quad_acc(float& ar, float& ai, float xv, float tx, float ty) {
    if (P == 0) { ar = fmaf(xv, tx, ar);  ai = fmaf(xv, ty, ai); }
    if (P == 1) { ar = fmaf(xv, ty, ar);  ai = fmaf(-xv, tx, ai); }   // *(-i)
    if (P == 2) { ar = fmaf(-xv, tx, ar); ai = fmaf(-xv, ty, ai); }   // *(-1)
    if (P == 3) { ar = fmaf(-xv, ty, ar); ai = fmaf(xv, tx, ai); }    // *(+i)
}

// xs layout: [64 rows][260 dwords] (256 w + 4 pad). Row stride 260 dwords
// => lane i's float4 starts at bank (4i+w) mod 32: every 8 consecutive lanes
// tile all 32 banks exactly once -> conflict-free ds_read_b128.
template<int KY0, int NKY>
__device__ __forceinline__ void fwdw_body(int lane, int row0, const float* xs,
                                          float2* __restrict__ A1)
{
    float ar[NKY], ai[NKY], tr[NKY], ti[NKY], sr[NKY], si[NKY];
#pragma unroll
    for (int j = 0; j < NKY; ++j) {
        ar[j] = 0.f; ai[j] = 0.f;
        const int kk = KY0 + j + 56;
        float a = kk * (1.f/128.f);
        sr[j] = cospif(a); si[j] = -sinpif(a);    // step e^{-2pi i kk/256}
        tr[j] = 1.f; ti[j] = 0.f;
    }
    const float4* xrow = (const float4*)(xs + lane*260);

    auto substep = [&](float xv0, float xv1, float xv2, float xv3) {
#pragma unroll
        for (int j = 0; j < NKY; ++j) {
            float tx = tr[j], ty = ti[j];
            const int pj = (KY0 + 56 + j) & 3;
            switch (pj) {
                case 0:
                    quad_acc<0>(ar[j], ai[j], xv0, tx, ty);
                    quad_acc<0>(ar[j], ai[j], xv1, tx, ty);
                    quad_acc<0>(ar[j], ai[j], xv2, tx, ty);
                    quad_acc<0>(ar[j], ai[j], xv3, tx, ty);
                    break;
                case 1:
                    quad_acc<0>(ar[j], ai[j], xv0, tx, ty);
                    quad_acc<1>(ar[j], ai[j], xv1, tx, ty);
                    quad_acc<2>(ar[j], ai[j], xv2, tx, ty);
                    quad_acc<3>(ar[j], ai[j], xv3, tx, ty);
                    break;
                case 2:
                    quad_acc<0>(ar[j], ai[j], xv0, tx, ty);
                    quad_acc<2>(ar[j], ai[j], xv1, tx, ty);
                    quad_acc<0>(ar[j], ai[j], xv2, tx, ty);
                    quad_acc<2>(ar[j], ai[j], xv3, tx, ty);
                    break;
                default:
                    quad_acc<0>(ar[j], ai[j], xv0, tx, ty);
                    quad_acc<3>(ar[j], ai[j], xv1, tx, ty);
                    quad_acc<2>(ar[j], ai[j], xv2, tx, ty);
                    quad_acc<1>(ar[j], ai[j], xv3, tx, ty);
                    break;
            }
            // advance twiddle: t *= step
            tr[j] = fmaf(tx, sr[j], -ty*si[j]);
            ti[j] = fmaf(tx, si[j],  ty*sr[j]);
        }
    };

#pragma unroll 4
    for (int wq = 0; wq < 16; ++wq) {
        float4 x0 = xrow[wq];            // w' = 4wq..4wq+3   (quadrant 0)
        float4 x1 = xrow[wq + 16];       // +64               (quadrant 1)
        float4 x2 = xrow[wq + 32];       // +128              (quadrant 2)
        float4 x3 = xrow[wq + 48];       // +192              (quadrant 3)
        substep(x0.x, x1.x, x2.x, x3.x);
        substep(x0.y, x1.y, x2.y, x3.y);
        substep(x0.z, x1.z, x2.z, x3.z);
        substep(x0.w, x1.w, x2.w, x3.w);
    }
    int row = row0 + lane;
#pragma unroll
    for (int j = 0; j < NKY; ++j)
        A1[(KY0 + j)*65536 + row] = make_float2(ar[j], ai[j]);
}

__global__ __launch_bounds__(256) void fwd_w_kernel(const float* __restrict__ x,
                                                    float2* __restrict__ A1)
{
    __shared__ float xs[64*260];        // [row][w] padded (260 dwords/row)
    int tid = threadIdx.x;
    int row0 = blockIdx.x * 64;
    const float2* xf2 = (const float2*)x;
    for (int i2 = tid; i2 < 8192; i2 += 256) {
        int r = i2 >> 7, w2 = i2 & 127;
        float2 v = xf2[(size_t)(row0 + r)*128 + w2];
        *(float2*)(xs + r*260 + 2*w2) = v;
    }
    __syncthreads();
    int lane = tid & 63, g = tid >> 6;
    if      (g == 0) fwdw_body<0, 5>(lane, row0, xs, A1);
    else if (g == 1) fwdw_body<5, 4>(lane, row0, xs, A1);
    else if (g == 2) fwdw_body<9, 4>(lane, row0, xs, A1);
    else             fwdw_body<13,4>(lane, row0, xs, A1);
}

// ================= forward partial DFT along h =================
__global__ __launch_bounds__(256) void fwd_h_kernel(const float2* __restrict__ A1,
                                                    float2* __restrict__ X)
{
    __shared__ float2 tbl[256];
    __shared__ float as_re[8*264];
    __shared__ float as_im[8*264];
    int tid = threadIdx.x;
    int ky = blockIdx.x >> 5, bi0 = (blockIdx.x & 31) * 8;
    tbl[tid] = make_float2(cospif(tid * (1.f/128.f)), -sinpif(tid * (1.f/128.f)));
    for (int idx = tid; idx < 2048; idx += 256) {
        int b = idx >> 8, h = idx & 255;
        float2 v = A1[ky*65536 + (bi0 + b)*256 + h];
        int ad = (h >> 5)*264 + (h & 31)*8 + b;
        as_re[ad] = v.x; as_im[ad] = v.y;
    }
    __syncthreads();
    int lane = tid & 63, g = tid >> 6;
    int bl = lane & 7, q = lane >> 3;
    int kx0 = g * 8;
    float2 acc[8];
#pragma unroll
    for (int j = 0; j < 8; ++j) acc[j] = make_float2(0.f, 0.f);
    int base = q*264 + bl;
    for (int hh = 0; hh < 32; ++hh) {
        float ar = as_re[base + hh*8];
        float ai = as_im[base + hh*8];
#pragma unroll
        for (int j = 0; j < 8; ++j) {
            int kk = kx0 + j + 112;
            float2 t = tbl[(kk * hh) & 255];      // wave-uniform broadcast
            acc[j].x = fmaf(ar, t.x, fmaf(-ai, t.y, acc[j].x));
            acc[j].y = fmaf(ar, t.y, fmaf( ai, t.x, acc[j].y));
        }
    }
    // epilogue twiddle e^{-2pi i jq/8} via recurrence; step from resident tbl
    float2 fstep = tbl[q * 32];                   // e^{-2pi i q/8}
    float2 f = make_float2(1.f, 0.f);
#pragma unroll
    for (int j = 0; j < 8; ++j) {
        float2 v = cmul(acc[j], f);
        v.x += __shfl_xor(v.x, 8);  v.y += __shfl_xor(v.y, 8);
        v.x += __shfl_xor(v.x, 16); v.y += __shfl_xor(v.y, 16);
        v.x += __shfl_xor(v.x, 32); v.y += __shfl_xor(v.y, 32);
        acc[j] = v;
        f = cmul(f, fstep);
    }
    if (q == 0) {
        const float inv = 1.f / 65536.f;
#pragma unroll
        for (int j = 0; j < 8; ++j)
            X[((kx0 + j)*17 + ky)*256 + bi0 + bl] =
                make_float2(acc[j].x * inv, acc[j].y * inv);
    }
}

// ================= per-mode channel mixing =================
__global__ __launch_bounds__(256) void mix_kernel(const float2* __restrict__ X,
                                                  const float2* __restrict__ W4,
                                                  float2* __restrict__ Mx)
{
    __shared__ float2 Xs[256];
    __shared__ float2 Ws[1024];
    int tid = threadIdx.x, mode = blockIdx.x;
    Xs[tid] = X[mode*256 + tid];
    for (int idx = tid; idx < 1024; idx += 256) Ws[idx] = W4[mode*1024 + idx];
    __syncthreads();
    int b = tid >> 5, o = tid & 31;
    float2 acc = make_float2(0.f, 0.f);
#pragma unroll
    for (int i = 0; i < 32; ++i)
        acc = cfma(Xs[b*32 + i], Ws[i*32 + o], acc);
    Mx[mode*256 + tid] = acc;
}

// ================= fused inverse, w-quadrant registers =================
// Grid 2048 = bo(256) x hc(8); block covers 32 h x 256 w.
// Phase 1 twiddles via per-thread recurrence (4 libm trig at init instead of
// 64 in-loop sincospi). Phase 2 C/S via recurrence, residue-class accumulate.
template<int KY0, int NK>
__device__ __forceinline__ void invh_part(int h, int hh, const float2* ms, float2* Ts)
{
    float2 acc[NK];
#pragma unroll
    for (int j = 0; j < NK; ++j) acc[j] = make_float2(0.f, 0.f);
    // t = e^{+2pi i (kx+112) h / 256}: init at kx=0, step e^{+2pi i h/256}
    int n0 = (112 * h) & 255;
    float tr = cospif(n0 * (1.f/128.f)), ti = sinpif(n0 * (1.f/128.f));
    float sr = cospif(h  * (1.f/128.f)), si = sinpif(h  * (1.f/128.f));
    for (int kx = 0; kx < 32; ++kx) {
#pragma unroll
        for (int j = 0; j < NK; ++j) {
            float2 mv = ms[kx*17 + KY0 + j];       // 2-way broadcast
            acc[j].x = fmaf(mv.x, tr, fmaf(-mv.y, ti, acc[j].x));
            acc[j].y = fmaf(mv.x, ti, fmaf( mv.y, tr, acc[j].y));
        }
        float ntr = fmaf(tr, sr, -ti*si);          // t *= step
        ti = fmaf(tr, si, ti*sr);
        tr = ntr;
    }
#pragma unroll
    for (int j = 0; j < NK; ++j) Ts[hh*18 + KY0 + j] = acc[j];
}

__global__ __launch_bounds__(256) void inv_kernel(const float2* __restrict__ Mx,
                                                  const int* __restrict__ q_bias,
                                                  const float* __restrict__ b_scale,
                                                  const float* __restrict__ b_min,
                                                  float* __restrict__ out)
{
    __shared__ float2 ms[544];
    __shared__ __align__(16) float2 Ts[32*18];     // rows padded to 18
    int tid = threadIdx.x;
    int bo = blockIdx.x & 255, hc = blockIdx.x >> 8;
    for (int idx = tid; idx < 544; idx += 256) ms[idx] = Mx[idx*256 + bo];
    __syncthreads();
    {   // phase 1: Ts[hh][ky] = sum_kx ms[kx][ky] e^{+2pi i (kx+112)h/256}
        int hh = tid & 31, g = tid >> 5;           // g in [0,8)
        int h = hc*32 + hh;
        if (g < 7) {
            switch (g) {
                case 0: invh_part<0, 2>(h, hh, ms, Ts); break;
                case 1: invh_part<2, 2>(h, hh, ms, Ts); break;
                case 2: invh_part<4, 2>(h, hh, ms, Ts); break;
                case 3: invh_part<6, 2>(h, hh, ms, Ts); break;
                case 4: invh_part<8, 2>(h, hh, ms, Ts); break;
                case 5: invh_part<10,2>(h, hh, ms, Ts); break;
                default:invh_part<12,2>(h, hh, ms, Ts); break;
            }
        } else {
            invh_part<14,3>(h, hh, ms, Ts);
        }
    }
    __syncthreads();
    {   // phase 2: out[h][w0+64q] = 2*Re(T[h]*e^{i th0}*i^{ky*q}) + bias
        int w0 = tid & 63, hs = tid >> 6;          // 4 h-subgroups of 8
        // C[ky]+iS[ky] = e^{+2pi i (ky+56) w0 / 256} via recurrence
        float C[17], S[17];
        {
            int n0 = (56 * w0) & 255;
            float tr = cospif(n0 * (1.f/128.f)), ti = sinpif(n0 * (1.f/128.f));
            float sr = cospif(w0 * (1.f/128.f)), si = sinpif(w0 * (1.f/128.f));
#pragma unroll
            for (int ky = 0; ky < 17; ++ky) {
                C[ky] = tr; S[ky] = ti;
                float ntr = fmaf(tr, sr, -ti*si);
                ti = fmaf(tr, si, ti*sr);
                tr = ntr;
            }
        }
        float bias = q_bias[bo & 31] * (*b_scale) + (*b_min);
        float* obase = out + (size_t)bo*65536 + (size_t)hc*32*256;

#pragma unroll
        for (int r = 0; r < 8; ++r) {
            int hh = hs*8 + r;
            const float4* tp = (const float4*)&Ts[hh*18];
            // residue-class accumulators: contribution of ky to quadrant q is
            // one of {+ur,-ui,-ur,+ui} keyed by p=(ky*q)&3; even ky never needs ui.
            float R0 = 0.f, R1 = 0.f, R2 = 0.f, R3 = 0.f, I1 = 0.f, I3 = 0.f;
#pragma unroll
            for (int kp = 0; kp < 9; ++kp) {
                float vx0, vy0, vx1 = 0.f, vy1 = 0.f;
                if (kp < 8) {
                    float4 v4 = tp[kp];
                    vx0 = v4.x; vy0 = v4.y; vx1 = v4.z; vy1 = v4.w;
                } else {
                    float2 v2 = Ts[hh*18 + 16];
                    vx0 = v2.x; vy0 = v2.y;
                }
#pragma unroll
                for (int half = 0; half < 2; ++half) {
                    if (kp == 8 && half == 1) break;
                    const int ky = 2*kp + half;
                    float vx = half ? vx1 : vx0;
                    float vy = half ? vy1 : vy0;
                    float ur = fmaf(vx, C[ky], -vy*S[ky]);
                    if ((ky & 1) == 0) {
                        if ((ky & 3) == 0) R0 += ur; else R2 += ur;
                    } else {
                        float ui = fmaf(vx, S[ky], vy*C[ky]);
                        if ((ky & 3) == 1) { R1 += ur; I1 += ui; }
                        else               { R3 += ur; I3 += ui; }
                    }
                }
            }
            // combine: q0=R0+R1+R2+R3; q1=R0-I1-R2+I3; q2=R0-R1+R2-R3; q3=R0+I1-R2-I3
            float e02 = R0 + R2, d02 = R0 - R2;
            float e13 = R1 + R3, di  = I3 - I1;
            float q0 = e02 + e13, q2 = e02 - e13;
            float q1 = d02 + di,  q3 = d02 - di;
            obase[hh*256 + w0]       = fmaf(2.f, q0, bias);
            obase[hh*256 + w0 + 64]  = fmaf(2.f, q1, bias);
            obase[hh*256 + w0 + 128] = fmaf(2.f, q2, bias);
            obase[hh*256 + w0 + 192] = fmaf(2.f, q3, bias);
        }
    }
}

extern "C" void kernel_launch(void* const* d_in, const int* in_sizes, int n_in,
                              void* d_out, int out_size, void* d_ws, size_t ws_size,
                              hipStream_t stream) {
    const float* x          = (const float*)d_in[0];
    const float* core_scale = (const float*)d_in[1];
    const float* core_min   = (const float*)d_in[2];
    const float* f_scales   = (const float*)d_in[3];
    const float* f_mins     = (const float*)d_in[4];
    const float* b_scale    = (const float*)d_in[5];
    const float* b_min      = (const float*)d_in[6];
    const int* q_core = (const int*)d_in[7];
    const int* q_f0   = (const int*)d_in[8];
    const int* q_f1   = (const int*)d_in[9];
    const int* q_f2   = (const int*)d_in[10];
    const int* q_f3   = (const int*)d_in[11];
    const int* q_bias = (const int*)d_in[12];
    float* out = (float*)d_out;

    float2* ws = (float2*)d_ws;
    float2* A1 = ws;                 // 1,114,112  [17][256 bi][256 h]
    float2* W4 = ws + 1114112;       //   557,056  [544][32][32]
    float2* X  = W4 + 557056;        //   139,264  [544][256]
    float2* Mx = X + 139264;         //   139,264  [544][256]
    float2* CL = Mx + 139264;        //    69,632  [17][16][256]
    (void)ws_size; (void)n_in; (void)in_sizes; (void)out_size;

    wprep_kernel<<<272, 256, 0, stream>>>(q_core, q_f3, core_scale, core_min,
                                          f_scales, f_mins, CL);
    weights_kernel<<<544, 256, 0, stream>>>(CL, q_f0, q_f1, q_f2,
                                            f_scales, f_mins, W4);
    fwd_w_kernel<<<1024, 256, 0, stream>>>(x, A1);
    fwd_h_kernel<<<544, 256, 0, stream>>>(A1, X);
    mix_kernel<<<544, 256, 0, stream>>>(X, W4, Mx);
    inv_kernel<<<2048, 256, 0, stream>>>(Mx, q_bias, b_scale, b_min, out);
}

// Round 4
// 202.824 us; speedup vs baseline: 1.1193x; 1.1193x over previous
//
#include <hip/hip_runtime.h>

// QuantizedSpectralConv on MI355X (gfx950).
// x [8,32,256,256] f32; Tucker: core[16,16,16,9] F0[32,16] F1[32,16] F2[32,16]
// F3[17,9] complex, deq = q*scale+min. Active window: kx in [112,144),
// ky in [56,73) of the (256,129) rfft2. norm="forward" (1/65536 on fwd).
//
// Workspace (float2):
//   A1 [17 ky][256 bi][256 h]; X [544 mode][256 bi]; W4 [544][32][32];
//   Mx [544 mode][256 bo];     CL [17 d][16 k][256 ij]  (F3-contracted core)
// LDS rule: addresses wave-uniform (broadcast) or lane-consecutive only.

__device__ __forceinline__ float2 cfma(float2 a, float2 b, float2 c) {
    c.x = fmaf(a.x, b.x, fmaf(-a.y, b.y, c.x));
    c.y = fmaf(a.x, b.y, fmaf(a.y, b.x, c.y));
    return c;
}
__device__ __forceinline__ float2 cmul(float2 a, float2 b) {
    return make_float2(a.x*b.x - a.y*b.y, a.x*b.y + a.y*b.x);
}

// ============ wprep: CL[d][k][ij] = sum_l core[ij,k,l] * F3[d,l] ============
__global__ __launch_bounds__(256) void wprep_kernel(
    const int* __restrict__ q_core, const int* __restrict__ q_f3,
    const float* __restrict__ core_scale, const float* __restrict__ core_min,
    const float* __restrict__ f_scales, const float* __restrict__ f_mins,
    float2* __restrict__ CL)
{
    int d = blockIdx.x >> 4, k = blockIdx.x & 15;   // grid 272
    int ij = threadIdx.x;
    float cs = *core_scale, cm = *core_min;
    float s3 = f_scales[3], m3 = f_mins[3];
    const int* qc = q_core + ((ij*16 + k)*9)*2;
    float2 acc = make_float2(0.f, 0.f);
#pragma unroll
    for (int l = 0; l < 9; ++l) {
        int2 q = *(const int2*)(qc + l*2);
        float2 ce = make_float2(q.x*cs + cm, q.y*cs + cm);
        float2 f3 = make_float2(q_f3[(d*9+l)*2]*s3 + m3, q_f3[(d*9+l)*2+1]*s3 + m3);
        acc = cfma(ce, f3, acc);
    }
    CL[(d*16 + k)*256 + ij] = acc;
}

// ============ weights: per-mode k/j/i contractions, CL coalesced ============
__global__ __launch_bounds__(256) void weights_kernel(
    const float2* __restrict__ CL, const int* __restrict__ q_f0,
    const int* __restrict__ q_f1, const int* __restrict__ q_f2,
    const float* __restrict__ f_scales, const float* __restrict__ f_mins,
    float2* __restrict__ W4)
{
    __shared__ float2 F0s[512], F1s[512];
    __shared__ float2 C2p[16*17];
    __shared__ float2 A2p[16*33];
    int t = threadIdx.x, m = blockIdx.x;
    int c = m / 17, d = m % 17;
    float s0 = f_scales[0], m0 = f_mins[0];
    float s1 = f_scales[1], m1 = f_mins[1];
    float s2 = f_scales[2], m2 = f_mins[2];

    for (int e = t; e < 512; e += 256) {
        F0s[e] = make_float2(q_f0[2*e]*s0 + m0, q_f0[2*e+1]*s0 + m0);
        F1s[e] = make_float2(q_f1[2*e]*s1 + m1, q_f1[2*e+1]*s1 + m1);
    }
    {   // phase 1: C2[i,j] = sum_k CL[d][k][ij] * F2[c,k]   (coalesced reads)
        float2 acc = make_float2(0.f, 0.f);
#pragma unroll
        for (int k = 0; k < 16; ++k) {
            float2 clv = CL[(d*16 + k)*256 + t];
            float2 f2 = make_float2(q_f2[(c*16+k)*2]*s2 + m2,
                                    q_f2[(c*16+k)*2+1]*s2 + m2);
            acc = cfma(clv, f2, acc);
        }
        __syncthreads();            // F0s/F1s ready; also before C2p write is fine
        C2p[(t >> 4)*17 + (t & 15)] = acc;
    }
    __syncthreads();
#pragma unroll
    for (int r = 0; r < 2; ++r) {   // phase 2: A2[i,b] = sum_j C2[i,j]*F1[b,j]
        int e = t + r*256; int i = e & 15, b = e >> 4;
        float2 acc = make_float2(0.f, 0.f);
#pragma unroll
        for (int j = 0; j < 16; ++j)
            acc = cfma(C2p[i*17 + j], F1s[b*16 + j], acc);
        A2p[i*33 + b] = acc;
    }
    __syncthreads();
    {   // phase 3: W4[m,a,b] = sum_i F0[a,i]*A2[i,b]
        int b = t & 31, a0 = t >> 5;
#pragma unroll
        for (int q = 0; q < 4; ++q) {
            int a = a0 + 8*q;
            float2 acc = make_float2(0.f, 0.f);
#pragma unroll
            for (int i = 0; i < 16; ++i)
                acc = cfma(F0s[a*16 + i], A2p[i*33 + b], acc);
            W4[m*1024 + a*32 + b] = acc;
        }
    }
}

// ================= forward partial DFT along w =================
// Register twiddle recurrence (no LDS table); quadrant signs wired.
template<int P>
__device__ __forceinline__ void quad_acc(float& ar, float& ai, float xv, float tx, float ty) {
    if (P == 0) { ar = fmaf(xv, tx, ar);  ai = fmaf(xv, ty, ai); }
    if (P == 1) { ar = fmaf(xv, ty, ar);  ai = fmaf(-xv, tx, ai); }   // *(-i)
    if (P == 2) { ar = fmaf(-xv, tx, ar); ai = fmaf(-xv, ty, ai); }   // *(-1)
    if (P == 3) { ar = fmaf(-xv, ty, ar); ai = fmaf(xv, tx, ai); }    // *(+i)
}

template<int KY0, int NKY>
__device__ __forceinline__ void fwdw_body(int lane, int row0, const float* xs,
                                          float2* __restrict__ A1)
{
    float ar[NKY], ai[NKY], tr[NKY], ti[NKY], sr[NKY], si[NKY];
#pragma unroll
    for (int j = 0; j < NKY; ++j) {
        ar[j] = 0.f; ai[j] = 0.f;
        const int kk = KY0 + j + 56;
        float a = kk * (1.f/128.f);
        sr[j] = cospif(a); si[j] = -sinpif(a);    // step e^{-2pi i kk/256}
        tr[j] = 1.f; ti[j] = 0.f;
    }
    // software prefetch: load iter w+1's samples before computing iter w,
    // so ds_read latency (~120cy) hides under ~110cy of FMA issue.
    float xv0 = xs[lane];
    float xv1 = xs[64*65 + lane];
    float xv2 = xs[128*65 + lane];
    float xv3 = xs[192*65 + lane];
    for (int w = 0; w < 64; ++w) {
        int wn = (w + 1) & 63;                    // w=63 prefetches dummies
        float nx0 = xs[wn*65 + lane];
        float nx1 = xs[(wn+64)*65 + lane];
        float nx2 = xs[(wn+128)*65 + lane];
        float nx3 = xs[(wn+192)*65 + lane];
#pragma unroll
        for (int j = 0; j < NKY; ++j) {
            float tx = tr[j], ty = ti[j];
            const int pj = (KY0 + 56 + j) & 3;
            switch (pj) {
                case 0:
                    quad_acc<0>(ar[j], ai[j], xv0, tx, ty);
                    quad_acc<0>(ar[j], ai[j], xv1, tx, ty);
                    quad_acc<0>(ar[j], ai[j], xv2, tx, ty);
                    quad_acc<0>(ar[j], ai[j], xv3, tx, ty);
                    break;
                case 1:
                    quad_acc<0>(ar[j], ai[j], xv0, tx, ty);
                    quad_acc<1>(ar[j], ai[j], xv1, tx, ty);
                    quad_acc<2>(ar[j], ai[j], xv2, tx, ty);
                    quad_acc<3>(ar[j], ai[j], xv3, tx, ty);
                    break;
                case 2:
                    quad_acc<0>(ar[j], ai[j], xv0, tx, ty);
                    quad_acc<2>(ar[j], ai[j], xv1, tx, ty);
                    quad_acc<0>(ar[j], ai[j], xv2, tx, ty);
                    quad_acc<2>(ar[j], ai[j], xv3, tx, ty);
                    break;
                default:
                    quad_acc<0>(ar[j], ai[j], xv0, tx, ty);
                    quad_acc<3>(ar[j], ai[j], xv1, tx, ty);
                    quad_acc<2>(ar[j], ai[j], xv2, tx, ty);
                    quad_acc<1>(ar[j], ai[j], xv3, tx, ty);
                    break;
            }
            // advance twiddle: t *= step
            tr[j] = fmaf(tx, sr[j], -ty*si[j]);
            ti[j] = fmaf(tx, si[j],  ty*sr[j]);
        }
        xv0 = nx0; xv1 = nx1; xv2 = nx2; xv3 = nx3;
    }
    int row = row0 + lane;
#pragma unroll
    for (int j = 0; j < NKY; ++j)
        A1[(KY0 + j)*65536 + row] = make_float2(ar[j], ai[j]);
}

__global__ __launch_bounds__(256) void fwd_w_kernel(const float* __restrict__ x,
                                                    float2* __restrict__ A1)
{
    __shared__ float xs[256*65];        // [w][row] padded, conflict-free
    int tid = threadIdx.x;
    int row0 = blockIdx.x * 64;
    const float2* xf2 = (const float2*)x;
    for (int i2 = tid; i2 < 8192; i2 += 256) {
        int r = i2 >> 7, w2 = i2 & 127;
        float2 v = xf2[(size_t)(row0 + r)*128 + w2];
        xs[(2*w2)*65 + r]   = v.x;
        xs[(2*w2+1)*65 + r] = v.y;
    }
    __syncthreads();
    int lane = tid & 63, g = tid >> 6;
    if      (g == 0) fwdw_body<0, 5>(lane, row0, xs, A1);
    else if (g == 1) fwdw_body<5, 4>(lane, row0, xs, A1);
    else if (g == 2) fwdw_body<9, 4>(lane, row0, xs, A1);
    else             fwdw_body<13,4>(lane, row0, xs, A1);
}

// ================= forward partial DFT along h =================
__global__ __launch_bounds__(256) void fwd_h_kernel(const float2* __restrict__ A1,
                                                    float2* __restrict__ X)
{
    __shared__ float2 tbl[256];
    __shared__ float as_re[8*264];
    __shared__ float as_im[8*264];
    int tid = threadIdx.x;
    int ky = blockIdx.x >> 5, bi0 = (blockIdx.x & 31) * 8;
    tbl[tid] = make_float2(cospif(tid * (1.f/128.f)), -sinpif(tid * (1.f/128.f)));
    for (int idx = tid; idx < 2048; idx += 256) {
        int b = idx >> 8, h = idx & 255;
        float2 v = A1[ky*65536 + (bi0 + b)*256 + h];
        int ad = (h >> 5)*264 + (h & 31)*8 + b;
        as_re[ad] = v.x; as_im[ad] = v.y;
    }
    __syncthreads();
    int lane = tid & 63, g = tid >> 6;
    int bl = lane & 7, q = lane >> 3;
    int kx0 = g * 8;
    float2 acc[8];
#pragma unroll
    for (int j = 0; j < 8; ++j) acc[j] = make_float2(0.f, 0.f);
    int base = q*264 + bl;
    for (int hh = 0; hh < 32; ++hh) {
        float ar = as_re[base + hh*8];
        float ai = as_im[base + hh*8];
#pragma unroll
        for (int j = 0; j < 8; ++j) {
            int kk = kx0 + j + 112;
            float2 t = tbl[(kk * hh) & 255];      // wave-uniform broadcast
            acc[j].x = fmaf(ar, t.x, fmaf(-ai, t.y, acc[j].x));
            acc[j].y = fmaf(ar, t.y, fmaf( ai, t.x, acc[j].y));
        }
    }
    // epilogue twiddle e^{-2pi i jq/8} via recurrence; step from resident tbl
    float2 fstep = tbl[q * 32];                   // e^{-2pi i q/8}
    float2 f = make_float2(1.f, 0.f);
#pragma unroll
    for (int j = 0; j < 8; ++j) {
        float2 v = cmul(acc[j], f);
        v.x += __shfl_xor(v.x, 8);  v.y += __shfl_xor(v.y, 8);
        v.x += __shfl_xor(v.x, 16); v.y += __shfl_xor(v.y, 16);
        v.x += __shfl_xor(v.x, 32); v.y += __shfl_xor(v.y, 32);
        acc[j] = v;
        f = cmul(f, fstep);
    }
    if (q == 0) {
        const float inv = 1.f / 65536.f;
#pragma unroll
        for (int j = 0; j < 8; ++j)
            X[((kx0 + j)*17 + ky)*256 + bi0 + bl] =
                make_float2(acc[j].x * inv, acc[j].y * inv);
    }
}

// ================= per-mode channel mixing =================
__global__ __launch_bounds__(256) void mix_kernel(const float2* __restrict__ X,
                                                  const float2* __restrict__ W4,
                                                  float2* __restrict__ Mx)
{
    __shared__ float2 Xs[256];
    __shared__ float2 Ws[1024];
    int tid = threadIdx.x, mode = blockIdx.x;
    Xs[tid] = X[mode*256 + tid];
    for (int idx = tid; idx < 1024; idx += 256) Ws[idx] = W4[mode*1024 + idx];
    __syncthreads();
    int b = tid >> 5, o = tid & 31;
    float2 acc = make_float2(0.f, 0.f);
#pragma unroll
    for (int i = 0; i < 32; ++i)
        acc = cfma(Xs[b*32 + i], Ws[i*32 + o], acc);
    Mx[mode*256 + tid] = acc;
}

// ================= fused inverse, w-quadrant registers =================
// Grid 2048 = bo(256) x hc(8); block covers 32 h x 256 w.
// Phase 1 twiddles via per-thread recurrence (4 libm trig at init instead of
// 64 in-loop sincospi). Phase 2 C/S via recurrence, residue-class accumulate.
template<int KY0, int NK>
__device__ __forceinline__ void invh_part(int h, int hh, const float2* ms, float2* Ts)
{
    float2 acc[NK];
#pragma unroll
    for (int j = 0; j < NK; ++j) acc[j] = make_float2(0.f, 0.f);
    // t = e^{+2pi i (kx+112) h / 256}: init at kx=0, step e^{+2pi i h/256}
    int n0 = (112 * h) & 255;
    float tr = cospif(n0 * (1.f/128.f)), ti = sinpif(n0 * (1.f/128.f));
    float sr = cospif(h  * (1.f/128.f)), si = sinpif(h  * (1.f/128.f));
    for (int kx = 0; kx < 32; ++kx) {
#pragma unroll
        for (int j = 0; j < NK; ++j) {
            float2 mv = ms[kx*17 + KY0 + j];       // 2-way broadcast
            acc[j].x = fmaf(mv.x, tr, fmaf(-mv.y, ti, acc[j].x));
            acc[j].y = fmaf(mv.x, ti, fmaf( mv.y, tr, acc[j].y));
        }
        float ntr = fmaf(tr, sr, -ti*si);          // t *= step
        ti = fmaf(tr, si, ti*sr);
        tr = ntr;
    }
#pragma unroll
    for (int j = 0; j < NK; ++j) Ts[hh*18 + KY0 + j] = acc[j];
}

__global__ __launch_bounds__(256) void inv_kernel(const float2* __restrict__ Mx,
                                                  const int* __restrict__ q_bias,
                                                  const float* __restrict__ b_scale,
                                                  const float* __restrict__ b_min,
                                                  float* __restrict__ out)
{
    __shared__ float2 ms[544];
    __shared__ __align__(16) float2 Ts[32*18];     // rows padded to 18
    int tid = threadIdx.x;
    int bo = blockIdx.x & 255, hc = blockIdx.x >> 8;
    for (int idx = tid; idx < 544; idx += 256) ms[idx] = Mx[idx*256 + bo];
    __syncthreads();
    {   // phase 1: Ts[hh][ky] = sum_kx ms[kx][ky] e^{+2pi i (kx+112)h/256}
        int hh = tid & 31, g = tid >> 5;           // g in [0,8)
        int h = hc*32 + hh;
        if (g < 7) {
            switch (g) {
                case 0: invh_part<0, 2>(h, hh, ms, Ts); break;
                case 1: invh_part<2, 2>(h, hh, ms, Ts); break;
                case 2: invh_part<4, 2>(h, hh, ms, Ts); break;
                case 3: invh_part<6, 2>(h, hh, ms, Ts); break;
                case 4: invh_part<8, 2>(h, hh, ms, Ts); break;
                case 5: invh_part<10,2>(h, hh, ms, Ts); break;
                default:invh_part<12,2>(h, hh, ms, Ts); break;
            }
        } else {
            invh_part<14,3>(h, hh, ms, Ts);
        }
    }
    __syncthreads();
    {   // phase 2: out[h][w0+64q] = 2*Re(T[h]*e^{i th0}*i^{ky*q}) + bias
        int w0 = tid & 63, hs = tid >> 6;          // 4 h-subgroups of 8
        // C[ky]+iS[ky] = e^{+2pi i (ky+56) w0 / 256} via recurrence
        float C[17], S[17];
        {
            int n0 = (56 * w0) & 255;
            float tr = cospif(n0 * (1.f/128.f)), ti = sinpif(n0 * (1.f/128.f));
            float sr = cospif(w0 * (1.f/128.f)), si = sinpif(w0 * (1.f/128.f));
#pragma unroll
            for (int ky = 0; ky < 17; ++ky) {
                C[ky] = tr; S[ky] = ti;
                float ntr = fmaf(tr, sr, -ti*si);
                ti = fmaf(tr, si, ti*sr);
                tr = ntr;
            }
        }
        float bias = q_bias[bo & 31] * (*b_scale) + (*b_min);
        float* obase = out + (size_t)bo*65536 + (size_t)hc*32*256;

#pragma unroll
        for (int r = 0; r < 8; ++r) {
            int hh = hs*8 + r;
            const float4* tp = (const float4*)&Ts[hh*18];
            // residue-class accumulators: contribution of ky to quadrant q is
            // one of {+ur,-ui,-ur,+ui} keyed by p=(ky*q)&3; even ky never needs ui.
            float R0 = 0.f, R1 = 0.f, R2 = 0.f, R3 = 0.f, I1 = 0.f, I3 = 0.f;
#pragma unroll
            for (int kp = 0; kp < 9; ++kp) {
                float vx0, vy0, vx1 = 0.f, vy1 = 0.f;
                if (kp < 8) {
                    float4 v4 = tp[kp];
                    vx0 = v4.x; vy0 = v4.y; vx1 = v4.z; vy1 = v4.w;
                } else {
                    float2 v2 = Ts[hh*18 + 16];
                    vx0 = v2.x; vy0 = v2.y;
                }
#pragma unroll
                for (int half = 0; half < 2; ++half) {
                    if (kp == 8 && half == 1) break;
                    const int ky = 2*kp + half;
                    float vx = half ? vx1 : vx0;
                    float vy = half ? vy1 : vy0;
                    float ur = fmaf(vx, C[ky], -vy*S[ky]);
                    if ((ky & 1) == 0) {
                        if ((ky & 3) == 0) R0 += ur; else R2 += ur;
                    } else {
                        float ui = fmaf(vx, S[ky], vy*C[ky]);
                        if ((ky & 3) == 1) { R1 += ur; I1 += ui; }
                        else               { R3 += ur; I3 += ui; }
                    }
                }
            }
            // combine: q0=R0+R1+R2+R3; q1=R0-I1-R2+I3; q2=R0-R1+R2-R3; q3=R0+I1-R2-I3
            float e02 = R0 + R2, d02 = R0 - R2;
            float e13 = R1 + R3, di  = I3 - I1;
            float q0 = e02 + e13, q2 = e02 - e13;
            float q1 = d02 + di,  q3 = d02 - di;
            obase[hh*256 + w0]       = fmaf(2.f, q0, bias);
            obase[hh*256 + w0 + 64]  = fmaf(2.f, q1, bias);
            obase[hh*256 + w0 + 128] = fmaf(2.f, q2, bias);
            obase[hh*256 + w0 + 192] = fmaf(2.f, q3, bias);
        }
    }
}

extern "C" void kernel_launch(void* const* d_in, const int* in_sizes, int n_in,
                              void* d_out, int out_size, void* d_ws, size_t ws_size,
                              hipStream_t stream) {
    const float* x          = (const float*)d_in[0];
    const float* core_scale = (const float*)d_in[1];
    const float* core_min   = (const float*)d_in[2];
    const float* f_scales   = (const float*)d_in[3];
    const float* f_mins     = (const float*)d_in[4];
    const float* b_scale    = (const float*)d_in[5];
    const float* b_min      = (const float*)d_in[6];
    const int* q_core = (const int*)d_in[7];
    const int* q_f0   = (const int*)d_in[8];
    const int* q_f1   = (const int*)d_in[9];
    const int* q_f2   = (const int*)d_in[10];
    const int* q_f3   = (const int*)d_in[11];
    const int* q_bias = (const int*)d_in[12];
    float* out = (float*)d_out;

    float2* ws = (float2*)d_ws;
    float2* A1 = ws;                 // 1,114,112  [17][256 bi][256 h]
    float2* W4 = ws + 1114112;       //   557,056  [544][32][32]
    float2* X  = W4 + 557056;        //   139,264  [544][256]
    float2* Mx = X + 139264;         //   139,264  [544][256]
    float2* CL = Mx + 139264;        //    69,632  [17][16][256]
    (void)ws_size; (void)n_in; (void)in_sizes; (void)out_size;

    wprep_kernel<<<272, 256, 0, stream>>>(q_core, q_f3, core_scale, core_min,
                                          f_scales, f_mins, CL);
    weights_kernel<<<544, 256, 0, stream>>>(CL, q_f0, q_f1, q_f2,
                                            f_scales, f_mins, W4);
    fwd_w_kernel<<<1024, 256, 0, stream>>>(x, A1);
    fwd_h_kernel<<<544, 256, 0, stream>>>(A1, X);
    mix_kernel<<<544, 256, 0, stream>>>(X, W4, Mx);
    inv_kernel<<<2048, 256, 0, stream>>>(Mx, q_bias, b_scale, b_min, out);
}

// Round 5
// 196.025 us; speedup vs baseline: 1.1581x; 1.0347x over previous
//
#include <hip/hip_runtime.h>

// QuantizedSpectralConv on MI355X (gfx950).
// x [8,32,256,256] f32; Tucker: core[16,16,16,9] F0[32,16] F1[32,16] F2[32,16]
// F3[17,9] complex, deq = q*scale+min. Active window: kx in [112,144),
// ky in [56,73) of the (256,129) rfft2. norm="forward" (1/65536 on fwd).
//
// Workspace (float2):
//   A1 [17 ky][256 bi][256 h]; X [544 mode][256 bi]; W4 [544][32][32];
//   Mx [544 mode][256 bo];     CL [17 d][16 k][256 ij]  (F3-contracted core)
// LDS rule: addresses wave-uniform (broadcast) or lane-consecutive only.

__device__ __forceinline__ float2 cfma(float2 a, float2 b, float2 c) {
    c.x = fmaf(a.x, b.x, fmaf(-a.y, b.y, c.x));
    c.y = fmaf(a.x, b.y, fmaf(a.y, b.x, c.y));
    return c;
}
__device__ __forceinline__ float2 cmul(float2 a, float2 b) {
    return make_float2(a.x*b.x - a.y*b.y, a.x*b.y + a.y*b.x);
}

// ============ wprep: CL[d][k][ij] = sum_l core[ij,k,l] * F3[d,l] ============
__global__ __launch_bounds__(256) void wprep_kernel(
    const int* __restrict__ q_core, const int* __restrict__ q_f3,
    const float* __restrict__ core_scale, const float* __restrict__ core_min,
    const float* __restrict__ f_scales, const float* __restrict__ f_mins,
    float2* __restrict__ CL)
{
    int d = blockIdx.x >> 4, k = blockIdx.x & 15;   // grid 272
    int ij = threadIdx.x;
    float cs = *core_scale, cm = *core_min;
    float s3 = f_scales[3], m3 = f_mins[3];
    const int* qc = q_core + ((ij*16 + k)*9)*2;
    float2 acc = make_float2(0.f, 0.f);
#pragma unroll
    for (int l = 0; l < 9; ++l) {
        int2 q = *(const int2*)(qc + l*2);
        float2 ce = make_float2(q.x*cs + cm, q.y*cs + cm);
        float2 f3 = make_float2(q_f3[(d*9+l)*2]*s3 + m3, q_f3[(d*9+l)*2+1]*s3 + m3);
        acc = cfma(ce, f3, acc);
    }
    CL[(d*16 + k)*256 + ij] = acc;
}

// ============ weights: per-mode k/j/i contractions, CL coalesced ============
__global__ __launch_bounds__(256) void weights_kernel(
    const float2* __restrict__ CL, const int* __restrict__ q_f0,
    const int* __restrict__ q_f1, const int* __restrict__ q_f2,
    const float* __restrict__ f_scales, const float* __restrict__ f_mins,
    float2* __restrict__ W4)
{
    __shared__ float2 F0s[512], F1s[512];
    __shared__ float2 C2p[16*17];
    __shared__ float2 A2p[16*33];
    int t = threadIdx.x, m = blockIdx.x;
    int c = m / 17, d = m % 17;
    float s0 = f_scales[0], m0 = f_mins[0];
    float s1 = f_scales[1], m1 = f_mins[1];
    float s2 = f_scales[2], m2 = f_mins[2];

    for (int e = t; e < 512; e += 256) {
        F0s[e] = make_float2(q_f0[2*e]*s0 + m0, q_f0[2*e+1]*s0 + m0);
        F1s[e] = make_float2(q_f1[2*e]*s1 + m1, q_f1[2*e+1]*s1 + m1);
    }
    {   // phase 1: C2[i,j] = sum_k CL[d][k][ij] * F2[c,k]   (coalesced reads)
        float2 acc = make_float2(0.f, 0.f);
#pragma unroll
        for (int k = 0; k < 16; ++k) {
            float2 clv = CL[(d*16 + k)*256 + t];
            float2 f2 = make_float2(q_f2[(c*16+k)*2]*s2 + m2,
                                    q_f2[(c*16+k)*2+1]*s2 + m2);
            acc = cfma(clv, f2, acc);
        }
        __syncthreads();            // F0s/F1s ready; also before C2p write is fine
        C2p[(t >> 4)*17 + (t & 15)] = acc;
    }
    __syncthreads();
#pragma unroll
    for (int r = 0; r < 2; ++r) {   // phase 2: A2[i,b] = sum_j C2[i,j]*F1[b,j]
        int e = t + r*256; int i = e & 15, b = e >> 4;
        float2 acc = make_float2(0.f, 0.f);
#pragma unroll
        for (int j = 0; j < 16; ++j)
            acc = cfma(C2p[i*17 + j], F1s[b*16 + j], acc);
        A2p[i*33 + b] = acc;
    }
    __syncthreads();
    {   // phase 3: W4[m,a,b] = sum_i F0[a,i]*A2[i,b]
        int b = t & 31, a0 = t >> 5;
#pragma unroll
        for (int q = 0; q < 4; ++q) {
            int a = a0 + 8*q;
            float2 acc = make_float2(0.f, 0.f);
#pragma unroll
            for (int i = 0; i < 16; ++i)
                acc = cfma(F0s[a*16 + i], A2p[i*33 + b], acc);
            W4[m*1024 + a*32 + b] = acc;
        }
    }
}

// ================= forward partial DFT along w =================
// Quadrant pre-combine + LDS twiddle table.
// A(ky) = sum_{w'<64} T(ky,w') * y_r(w'),  r = ky mod 4, where
//   y0 = (x0+x2)+(x1+x3)  (real)      y2 = (x0+x2)-(x1+x3)  (real)
//   y1 = d02 - i*d13                  y3 = d02 + i*d13
// (xq = x[w'+64q]; d02=x0-x2, d13=x1-x3). Combines computed during staging.
// Twiddles T = e^{-2pi i ky w'/256} from a 17x64 LDS table (wave-uniform
// broadcast reads) -- replaces the 4-FMA-per-(ky,w') register recurrence.
__global__ __launch_bounds__(256) void fwd_w_kernel(const float* __restrict__ x,
                                                    float2* __restrict__ A1)
{
    __shared__ float ys0[64*65], ys2[64*65], yd02[64*65], yd13[64*65];
    __shared__ float2 twl[17*64];       // [ki][w'], ki = ky-56
    int tid = threadIdx.x;
    int row0 = blockIdx.x * 64;

    for (int i = tid; i < 17*64; i += 256) {
        int ki = i >> 6, wp = i & 63;
        int n = ((56 + ki) * wp) & 255;
        float a = n * (1.f/128.f);
        twl[i] = make_float2(cospif(a), -sinpif(a));
    }
    const float2* xf2 = (const float2*)x;
    for (int i2 = tid; i2 < 2048; i2 += 256) {
        int r = i2 >> 5, w2 = i2 & 31;  // row, float2-index within quadrant
        const float2* xb = xf2 + (size_t)(row0 + r) * 128 + w2;
        float2 a0 = xb[0], a1 = xb[32], a2 = xb[64], a3 = xb[96];
        int ad = (2*w2)*65 + r;         // plane [w'][row], row-consecutive
        float s02 = a0.x + a2.x, s13 = a1.x + a3.x;
        ys0[ad] = s02 + s13;  ys2[ad] = s02 - s13;
        yd02[ad] = a0.x - a2.x;  yd13[ad] = a1.x - a3.x;
        s02 = a0.y + a2.y;  s13 = a1.y + a3.y;
        ys0[ad+65] = s02 + s13;  ys2[ad+65] = s02 - s13;
        yd02[ad+65] = a0.y - a2.y;  yd13[ad+65] = a1.y - a3.y;
    }
    __syncthreads();

    int lane = tid & 63, g = tid >> 6;  // wave g owns residue class g
    int row = row0 + lane;
    if (g == 0) {                       // ky = 56,60,64,68,72 : real y0
        float2 acc[5] = {};
        for (int wp = 0; wp < 64; ++wp) {
            float y = ys0[wp*65 + lane];
#pragma unroll
            for (int j = 0; j < 5; ++j) {
                float2 t = twl[(4*j)*64 + wp];
                acc[j].x = fmaf(y, t.x, acc[j].x);
                acc[j].y = fmaf(y, t.y, acc[j].y);
            }
        }
#pragma unroll
        for (int j = 0; j < 5; ++j) A1[(4*j)*65536 + row] = acc[j];
    } else if (g == 2) {                // ky = 58,62,66,70 : real y2
        float2 acc[4] = {};
        for (int wp = 0; wp < 64; ++wp) {
            float y = ys2[wp*65 + lane];
#pragma unroll
            for (int j = 0; j < 4; ++j) {
                float2 t = twl[(2+4*j)*64 + wp];
                acc[j].x = fmaf(y, t.x, acc[j].x);
                acc[j].y = fmaf(y, t.y, acc[j].y);
            }
        }
#pragma unroll
        for (int j = 0; j < 4; ++j) A1[(2+4*j)*65536 + row] = acc[j];
    } else if (g == 1) {                // ky = 57,61,65,69 : y1 = a - i b
        float2 acc[4] = {};
        for (int wp = 0; wp < 64; ++wp) {
            float a = yd02[wp*65 + lane], b = yd13[wp*65 + lane];
#pragma unroll
            for (int j = 0; j < 4; ++j) {
                float2 t = twl[(1+4*j)*64 + wp];
                acc[j].x = fmaf(t.x, a, fmaf( t.y, b, acc[j].x));
                acc[j].y = fmaf(t.y, a, fmaf(-t.x, b, acc[j].y));
            }
        }
#pragma unroll
        for (int j = 0; j < 4; ++j) A1[(1+4*j)*65536 + row] = acc[j];
    } else {                            // ky = 59,63,67,71 : y3 = a + i b
        float2 acc[4] = {};
        for (int wp = 0; wp < 64; ++wp) {
            float a = yd02[wp*65 + lane], b = yd13[wp*65 + lane];
#pragma unroll
            for (int j = 0; j < 4; ++j) {
                float2 t = twl[(3+4*j)*64 + wp];
                acc[j].x = fmaf(t.x, a, fmaf(-t.y, b, acc[j].x));
                acc[j].y = fmaf(t.y, a, fmaf( t.x, b, acc[j].y));
            }
        }
#pragma unroll
        for (int j = 0; j < 4; ++j) A1[(3+4*j)*65536 + row] = acc[j];
    }
}

// ================= forward partial DFT along h =================
__global__ __launch_bounds__(256) void fwd_h_kernel(const float2* __restrict__ A1,
                                                    float2* __restrict__ X)
{
    __shared__ float2 tbl[256];
    __shared__ float as_re[8*264];
    __shared__ float as_im[8*264];
    int tid = threadIdx.x;
    int ky = blockIdx.x >> 5, bi0 = (blockIdx.x & 31) * 8;
    tbl[tid] = make_float2(cospif(tid * (1.f/128.f)), -sinpif(tid * (1.f/128.f)));
    for (int idx = tid; idx < 2048; idx += 256) {
        int b = idx >> 8, h = idx & 255;
        float2 v = A1[ky*65536 + (bi0 + b)*256 + h];
        int ad = (h >> 5)*264 + (h & 31)*8 + b;
        as_re[ad] = v.x; as_im[ad] = v.y;
    }
    __syncthreads();
    int lane = tid & 63, g = tid >> 6;
    int bl = lane & 7, q = lane >> 3;
    int kx0 = g * 8;
    float2 acc[8];
#pragma unroll
    for (int j = 0; j < 8; ++j) acc[j] = make_float2(0.f, 0.f);
    int base = q*264 + bl;
    for (int hh = 0; hh < 32; ++hh) {
        float ar = as_re[base + hh*8];
        float ai = as_im[base + hh*8];
#pragma unroll
        for (int j = 0; j < 8; ++j) {
            int kk = kx0 + j + 112;
            float2 t = tbl[(kk * hh) & 255];      // wave-uniform broadcast
            acc[j].x = fmaf(ar, t.x, fmaf(-ai, t.y, acc[j].x));
            acc[j].y = fmaf(ar, t.y, fmaf( ai, t.x, acc[j].y));
        }
    }
    // epilogue twiddle e^{-2pi i jq/8} via recurrence; step from resident tbl
    float2 fstep = tbl[q * 32];                   // e^{-2pi i q/8}
    float2 f = make_float2(1.f, 0.f);
#pragma unroll
    for (int j = 0; j < 8; ++j) {
        float2 v = cmul(acc[j], f);
        v.x += __shfl_xor(v.x, 8);  v.y += __shfl_xor(v.y, 8);
        v.x += __shfl_xor(v.x, 16); v.y += __shfl_xor(v.y, 16);
        v.x += __shfl_xor(v.x, 32); v.y += __shfl_xor(v.y, 32);
        acc[j] = v;
        f = cmul(f, fstep);
    }
    if (q == 0) {
        const float inv = 1.f / 65536.f;
#pragma unroll
        for (int j = 0; j < 8; ++j)
            X[((kx0 + j)*17 + ky)*256 + bi0 + bl] =
                make_float2(acc[j].x * inv, acc[j].y * inv);
    }
}

// ================= per-mode channel mixing =================
__global__ __launch_bounds__(256) void mix_kernel(const float2* __restrict__ X,
                                                  const float2* __restrict__ W4,
                                                  float2* __restrict__ Mx)
{
    __shared__ float2 Xs[256];
    __shared__ float2 Ws[1024];
    int tid = threadIdx.x, mode = blockIdx.x;
    Xs[tid] = X[mode*256 + tid];
    for (int idx = tid; idx < 1024; idx += 256) Ws[idx] = W4[mode*1024 + idx];
    __syncthreads();
    int b = tid >> 5, o = tid & 31;
    float2 acc = make_float2(0.f, 0.f);
#pragma unroll
    for (int i = 0; i < 32; ++i)
        acc = cfma(Xs[b*32 + i], Ws[i*32 + o], acc);
    Mx[mode*256 + tid] = acc;
}

// ================= fused inverse, w-quadrant registers =================
// Grid 2048 = bo(256) x hc(8); block covers 32 h x 256 w.
// Phase 1 twiddles via per-thread recurrence (4 libm trig at init instead of
// 64 in-loop sincospi). Phase 2 C/S via recurrence, residue-class accumulate.
template<int KY0, int NK>
__device__ __forceinline__ void invh_part(int h, int hh, const float2* ms, float2* Ts)
{
    float2 acc[NK];
#pragma unroll
    for (int j = 0; j < NK; ++j) acc[j] = make_float2(0.f, 0.f);
    // t = e^{+2pi i (kx+112) h / 256}: init at kx=0, step e^{+2pi i h/256}
    int n0 = (112 * h) & 255;
    float tr = cospif(n0 * (1.f/128.f)), ti = sinpif(n0 * (1.f/128.f));
    float sr = cospif(h  * (1.f/128.f)), si = sinpif(h  * (1.f/128.f));
    for (int kx = 0; kx < 32; ++kx) {
#pragma unroll
        for (int j = 0; j < NK; ++j) {
            float2 mv = ms[kx*17 + KY0 + j];       // 2-way broadcast
            acc[j].x = fmaf(mv.x, tr, fmaf(-mv.y, ti, acc[j].x));
            acc[j].y = fmaf(mv.x, ti, fmaf( mv.y, tr, acc[j].y));
        }
        float ntr = fmaf(tr, sr, -ti*si);          // t *= step
        ti = fmaf(tr, si, ti*sr);
        tr = ntr;
    }
#pragma unroll
    for (int j = 0; j < NK; ++j) Ts[hh*18 + KY0 + j] = acc[j];
}

__global__ __launch_bounds__(256) void inv_kernel(const float2* __restrict__ Mx,
                                                  const int* __restrict__ q_bias,
                                                  const float* __restrict__ b_scale,
                                                  const float* __restrict__ b_min,
                                                  float* __restrict__ out)
{
    __shared__ float2 ms[544];
    __shared__ __align__(16) float2 Ts[32*18];     // rows padded to 18
    int tid = threadIdx.x;
    int bo = blockIdx.x & 255, hc = blockIdx.x >> 8;
    for (int idx = tid; idx < 544; idx += 256) ms[idx] = Mx[idx*256 + bo];
    __syncthreads();
    {   // phase 1: Ts[hh][ky] = sum_kx ms[kx][ky] e^{+2pi i (kx+112)h/256}
        int hh = tid & 31, g = tid >> 5;           // g in [0,8)
        int h = hc*32 + hh;
        if (g < 7) {
            switch (g) {
                case 0: invh_part<0, 2>(h, hh, ms, Ts); break;
                case 1: invh_part<2, 2>(h, hh, ms, Ts); break;
                case 2: invh_part<4, 2>(h, hh, ms, Ts); break;
                case 3: invh_part<6, 2>(h, hh, ms, Ts); break;
                case 4: invh_part<8, 2>(h, hh, ms, Ts); break;
                case 5: invh_part<10,2>(h, hh, ms, Ts); break;
                default:invh_part<12,2>(h, hh, ms, Ts); break;
            }
        } else {
            invh_part<14,3>(h, hh, ms, Ts);
        }
    }
    __syncthreads();
    {   // phase 2: out[h][w0+64q] = 2*Re(T[h]*e^{i th0}*i^{ky*q}) + bias
        int w0 = tid & 63, hs = tid >> 6;          // 4 h-subgroups of 8
        // C[ky]+iS[ky] = e^{+2pi i (ky+56) w0 / 256} via recurrence
        float C[17], S[17];
        {
            int n0 = (56 * w0) & 255;
            float tr = cospif(n0 * (1.f/128.f)), ti = sinpif(n0 * (1.f/128.f));
            float sr = cospif(w0 * (1.f/128.f)), si = sinpif(w0 * (1.f/128.f));
#pragma unroll
            for (int ky = 0; ky < 17; ++ky) {
                C[ky] = tr; S[ky] = ti;
                float ntr = fmaf(tr, sr, -ti*si);
                ti = fmaf(tr, si, ti*sr);
                tr = ntr;
            }
        }
        float bias = q_bias[bo & 31] * (*b_scale) + (*b_min);
        float* obase = out + (size_t)bo*65536 + (size_t)hc*32*256;

#pragma unroll
        for (int r = 0; r < 8; ++r) {
            int hh = hs*8 + r;
            const float4* tp = (const float4*)&Ts[hh*18];
            // residue-class accumulators: contribution of ky to quadrant q is
            // one of {+ur,-ui,-ur,+ui} keyed by p=(ky*q)&3; even ky never needs ui.
            float R0 = 0.f, R1 = 0.f, R2 = 0.f, R3 = 0.f, I1 = 0.f, I3 = 0.f;
#pragma unroll
            for (int kp = 0; kp < 9; ++kp) {
                float vx0, vy0, vx1 = 0.f, vy1 = 0.f;
                if (kp < 8) {
                    float4 v4 = tp[kp];
                    vx0 = v4.x; vy0 = v4.y; vx1 = v4.z; vy1 = v4.w;
                } else {
                    float2 v2 = Ts[hh*18 + 16];
                    vx0 = v2.x; vy0 = v2.y;
                }
#pragma unroll
                for (int half = 0; half < 2; ++half) {
                    if (kp == 8 && half == 1) break;
                    const int ky = 2*kp + half;
                    float vx = half ? vx1 : vx0;
                    float vy = half ? vy1 : vy0;
                    float ur = fmaf(vx, C[ky], -vy*S[ky]);
                    if ((ky & 1) == 0) {
                        if ((ky & 3) == 0) R0 += ur; else R2 += ur;
                    } else {
                        float ui = fmaf(vx, S[ky], vy*C[ky]);
                        if ((ky & 3) == 1) { R1 += ur; I1 += ui; }
                        else               { R3 += ur; I3 += ui; }
                    }
                }
            }
            // combine: q0=R0+R1+R2+R3; q1=R0-I1-R2+I3; q2=R0-R1+R2-R3; q3=R0+I1-R2-I3
            float e02 = R0 + R2, d02 = R0 - R2;
            float e13 = R1 + R3, di  = I3 - I1;
            float q0 = e02 + e13, q2 = e02 - e13;
            float q1 = d02 + di,  q3 = d02 - di;
            obase[hh*256 + w0]       = fmaf(2.f, q0, bias);
            obase[hh*256 + w0 + 64]  = fmaf(2.f, q1, bias);
            obase[hh*256 + w0 + 128] = fmaf(2.f, q2, bias);
            obase[hh*256 + w0 + 192] = fmaf(2.f, q3, bias);
        }
    }
}

extern "C" void kernel_launch(void* const* d_in, const int* in_sizes, int n_in,
                              void* d_out, int out_size, void* d_ws, size_t ws_size,
                              hipStream_t stream) {
    const float* x          = (const float*)d_in[0];
    const float* core_scale = (const float*)d_in[1];
    const float* core_min   = (const float*)d_in[2];
    const float* f_scales   = (const float*)d_in[3];
    const float* f_mins     = (const float*)d_in[4];
    const float* b_scale    = (const float*)d_in[5];
    const float* b_min      = (const float*)d_in[6];
    const int* q_core = (const int*)d_in[7];
    const int* q_f0   = (const int*)d_in[8];
    const int* q_f1   = (const int*)d_in[9];
    const int* q_f2   = (const int*)d_in[10];
    const int* q_f3   = (const int*)d_in[11];
    const int* q_bias = (const int*)d_in[12];
    float* out = (float*)d_out;

    float2* ws = (float2*)d_ws;
    float2* A1 = ws;                 // 1,114,112  [17][256 bi][256 h]
    float2* W4 = ws + 1114112;       //   557,056  [544][32][32]
    float2* X  = W4 + 557056;        //   139,264  [544][256]
    float2* Mx = X + 139264;         //   139,264  [544][256]
    float2* CL = Mx + 139264;        //    69,632  [17][16][256]
    (void)ws_size; (void)n_in; (void)in_sizes; (void)out_size;

    wprep_kernel<<<272, 256, 0, stream>>>(q_core, q_f3, core_scale, core_min,
                                          f_scales, f_mins, CL);
    weights_kernel<<<544, 256, 0, stream>>>(CL, q_f0, q_f1, q_f2,
                                            f_scales, f_mins, W4);
    fwd_w_kernel<<<1024, 256, 0, stream>>>(x, A1);
    fwd_h_kernel<<<544, 256, 0, stream>>>(A1, X);
    mix_kernel<<<544, 256, 0, stream>>>(X, W4, Mx);
    inv_kernel<<<2048, 256, 0, stream>>>(Mx, q_bias, b_scale, b_min, out);
}